// Round 6
// baseline (994.548 us; speedup 1.0000x reference)
//
#include <hip/hip_runtime.h>

typedef unsigned short ushort_t;
typedef __attribute__((ext_vector_type(8))) short short8;
typedef __attribute__((ext_vector_type(4))) float f32x4;

#define MTOT 28672   // B*S = 8*3584
#define H_   1024

static __device__ __forceinline__ float b2f(ushort_t u) {
    return __uint_as_float(((unsigned)u) << 16);
}
static __device__ __forceinline__ ushort_t f2b(float f) {
    unsigned u = __float_as_uint(f);
    u += 0x7fffu + ((u >> 16) & 1u);
    return (ushort_t)(u >> 16);
}

#define GLOAD(src, dst) __builtin_amdgcn_global_load_lds( \
    (const __attribute__((address_space(1))) void*)(src), \
    (__attribute__((address_space(3))) void*)(dst), 16, 0, 0)
#define MFMA16(a, b, c) __builtin_amdgcn_mfma_f32_16x16x32_bf16(a, b, c, 0, 0, 0)

// ---------------- fp32 -> bf16 conversion (n % 1024 == 0), 4 elems/thread ----------------
__global__ __launch_bounds__(256)
void f2b_kernel(const float* __restrict__ in, ushort_t* __restrict__ out)
{
    size_t i = (size_t)blockIdx.x * 256 + threadIdx.x;
    float4 v = ((const float4*)in)[i];
    ushort4 o;
    o.x = f2b(v.x); o.y = f2b(v.y); o.z = f2b(v.z); o.w = f2b(v.w);
    ((ushort4*)out)[i] = o;
}

// ---------------- bf16 GEMM v6: BM=BN=256, 8 waves (2m x 4n, 128x64 each) ----------------
// K32-ring staging (4 slots x {A 16KB + B 16KB}, 3 in flight, counted vmcnt) +
// m201-style phase straddle: per K32 step, TWO phases of 16 MFMA each; each phase's
// ds_reads are issued BEFORE its barrier, MFMA cluster after -> on each SIMD one wave's
// MFMA overlaps the sibling's ds_read/gload issue; setprio(1) biases the MFMA wave.
//   phase A: read bv[0..3]+avlo[0..3] (slot t) ; stage slot t+3 ; barrier ; 16 MFMA (m0-3)
//   phase B: read avhi[0..3] (slot t) ; vmcnt(slot t+1 resident) ; barrier ; 16 MFMA (m4-7)
// Residency: slot t+1's vmcnt sits before barrier-B(t), so phase-A(t+1) pre-barrier reads
// are safe. Tail: vmcnt(8/4/0) as outstanding loads drain.
// A [M,K] bf16 rm, Bt [N,K] bf16 rm. M%256==0, N%256==0, K%32==0, K>=96.
// Region layout: row r (256) x 4 chunks(16B); chunk kk at pos = kk ^ ((r>>1)&3) (0 conflicts).
// Swapped-operand MFMA: lane (fr,kg) of frag (m,n) holds row wm*128+m*16+fr,
// cols wn*64+n*16+kg*4+{0..3}; epilogue transposes via swizzled LDS -> 64B stores.
template<int EPI, typename ResT>
__global__ __launch_bounds__(512, 1)
void gemm_bt(const ushort_t* __restrict__ A, const ushort_t* __restrict__ Bt,
             const float* __restrict__ bias, const ResT* __restrict__ Res,
             ushort_t* __restrict__ C, int N, int K, int GX)
{
    __shared__ __align__(16) ushort_t lds[4][2][8192];   // [slot][A/B][16KB] = 128 KB
    const int tid  = threadIdx.x;
    const int wave = tid >> 6;
    const int lane = tid & 63;
    const int wm = wave >> 2, wn = wave & 3;   // 2x4 waves, each 128 rows x 64 cols
    const int fr = lane & 15, kg = lane >> 4;

    // bijective XCD-chunked swizzle (m204 form)
    const int nwg = gridDim.x;
    const int xcd = blockIdx.x & 7, ofs = blockIdx.x >> 3;
    const int q8 = nwg >> 3, r8 = nwg & 7;
    const int wg = (xcd < r8 ? xcd * (q8 + 1) : r8 * (q8 + 1) + (xcd - r8) * q8) + ofs;
    const long row0 = (long)(wg / GX) * 256;
    const long col0 = (long)(wg % GX) * 256;

    const int NT = K >> 5;   // K32 steps

    // ---- staging: per region, 1024 chunks = 512 thr x 2 rounds (round1 = +128 rows) ----
    const int sr_ = tid >> 2;
    const int kk_ = (tid & 3) ^ ((sr_ >> 1) & 3);
    const ushort_t* pa = A  + (row0 + sr_) * (size_t)K + kk_ * 8;
    const ushort_t* pb = Bt + (col0 + sr_) * (size_t)K + kk_ * 8;
    const size_t rstep = (size_t)128 * K;

    // prologue: slots 0,1,2 (A,A,B,B per slot -> strict issue order for vmcnt)
    #pragma unroll
    for (int r = 0; r < 3; ++r) {
        ushort_t* dA = &lds[r][0][0] + wave * 512;
        ushort_t* dB = &lds[r][1][0] + wave * 512;
        GLOAD(pa + r * 32, dA); GLOAD(pa + r * 32 + rstep, dA + 4096);
        GLOAD(pb + r * 32, dB); GLOAD(pb + r * 32 + rstep, dB + 4096);
    }
    asm volatile("s_waitcnt vmcnt(8)" ::: "memory");   // slot 0 resident
    asm volatile("s_barrier" ::: "memory");

    // per-lane ds_read byte offsets within a region half
    const int pos2  = kg ^ ((fr >> 1) & 3);
    const int abase = (wm * 128 + fr) * 64 + pos2 * 16;   // + m*1024
    const int bbase = (wn * 64  + fr) * 64 + pos2 * 16;   // + n*1024

    f32x4 acc[8][4] = {};

    for (int t = 0; t < NT; ++t) {
        const int s = t & 3;
        const char* rA = (const char*)&lds[s][0][0];
        const char* rB = (const char*)&lds[s][1][0];

        // ---- phase A: reads (slot t, resident since previous barrier), stage t+3 ----
        short8 bv[4], avlo[4], avhi[4];
        #pragma unroll
        for (int j = 0; j < 4; ++j) bv[j]   = *(const short8*)(rB + bbase + j * 1024);
        #pragma unroll
        for (int i = 0; i < 4; ++i) avlo[i] = *(const short8*)(rA + abase + i * 1024);
        if (t + 3 < NT) {
            const int s3 = (t + 3) & 3;
            const size_t go = (size_t)(t + 3) * 32;
            ushort_t* dA = &lds[s3][0][0] + wave * 512;
            ushort_t* dB = &lds[s3][1][0] + wave * 512;
            GLOAD(pa + go, dA); GLOAD(pa + go + rstep, dA + 4096);
            GLOAD(pb + go, dB); GLOAD(pb + go + rstep, dB + 4096);
        }
        asm volatile("s_barrier" ::: "memory");
        __builtin_amdgcn_s_setprio(1);
        #pragma unroll
        for (int i = 0; i < 4; ++i)
            #pragma unroll
            for (int j = 0; j < 4; ++j) acc[i][j] = MFMA16(bv[j], avlo[i], acc[i][j]);
        __builtin_amdgcn_s_setprio(0);

        // ---- phase B: reads m4-7 (slot t), vmcnt so slot t+1 resident after barrier ----
        #pragma unroll
        for (int i = 0; i < 4; ++i) avhi[i] = *(const short8*)(rA + abase + (4 + i) * 1024);
        if (t + 4 <= NT - 1)      { asm volatile("s_waitcnt vmcnt(8)" ::: "memory"); }
        else if (t + 3 == NT - 1) { asm volatile("s_waitcnt vmcnt(4)" ::: "memory"); }
        else if (t + 2 == NT - 1) { asm volatile("s_waitcnt vmcnt(0)" ::: "memory"); }
        asm volatile("s_barrier" ::: "memory");
        __builtin_amdgcn_s_setprio(1);
        #pragma unroll
        for (int i = 0; i < 4; ++i)
            #pragma unroll
            for (int j = 0; j < 4; ++j) acc[4 + i][j] = MFMA16(bv[j], avhi[i], acc[4 + i][j]);
        __builtin_amdgcn_s_setprio(0);
    }

    // ---- epilogue: swapped layout -> swizzled LDS bf16 tile -> coalesced stores ----
    __syncthreads();   // all K-loop LDS reads complete before overwrite
    char* L = (char*)&lds[0][0][0];   // [256 rows][512 B], chunk16 ^= (row&31)

    // bias per lane: 4 consecutive cols per n-frag
    float4 bias4[4];
    #pragma unroll
    for (int n = 0; n < 4; ++n)
        bias4[n] = *(const float4*)&bias[col0 + wn * 64 + n * 16 + kg * 4];

    #pragma unroll
    for (int m = 0; m < 8; ++m) {
        const int row_t = wm * 128 + m * 16 + fr;
        const long grow = (row0 + row_t) * (long)N;
        #pragma unroll
        for (int n = 0; n < 4; ++n) {
            const int colr = wn * 64 + n * 16 + kg * 4;     // col within tile
            float v0 = acc[m][n][0] + bias4[n].x;
            float v1 = acc[m][n][1] + bias4[n].y;
            float v2 = acc[m][n][2] + bias4[n].z;
            float v3 = acc[m][n][3] + bias4[n].w;
            if constexpr (EPI == 1) {
                v0 = fmaxf(v0, 0.f); v1 = fmaxf(v1, 0.f);
                v2 = fmaxf(v2, 0.f); v3 = fmaxf(v3, 0.f);
            }
            if constexpr (EPI == 2) {
                if constexpr (sizeof(ResT) == 4) {
                    float4 r4 = *(const float4*)&Res[grow + col0 + colr];
                    v0 += r4.x; v1 += r4.y; v2 += r4.z; v3 += r4.w;
                } else {
                    ushort4 r4 = *(const ushort4*)&Res[grow + col0 + colr];
                    v0 += b2f(r4.x); v1 += b2f(r4.y); v2 += b2f(r4.z); v3 += b2f(r4.w);
                }
            }
            ushort4 pk; pk.x = f2b(v0); pk.y = f2b(v1); pk.z = f2b(v2); pk.w = f2b(v3);
            const int cbyte = colr * 2;                      // 0..510
            const int chunk = cbyte >> 4;                    // 0..31
            const int addr  = row_t * 512 + ((chunk ^ (row_t & 31)) << 4) + (cbyte & 15);
            *(ushort4*)(L + addr) = pk;
        }
    }
    __syncthreads();

    // readback: 4 lanes per row -> 64B contiguous store segments
    #pragma unroll
    for (int p = 0; p < 2; ++p) {
        const int row_t = p * 128 + (tid >> 2);
        const long grow = (row0 + row_t) * (long)N + col0;
        #pragma unroll
        for (int k = 0; k < 8; ++k) {
            const int chunk = k * 4 + (tid & 3);
            short8 d = *(const short8*)(L + row_t * 512 + ((chunk ^ (row_t & 31)) << 4));
            *(short8*)&C[grow + chunk * 8] = d;
        }
    }
}

// ---------------- per-(window,head) attention: q,k,v [7,64]; one wave per block ----------------
__global__ __launch_bounds__(64)
void attn_kernel(const ushort_t* __restrict__ qkv, ushort_t* __restrict__ o)
{
    const int bid  = blockIdx.x;
    const int win  = bid >> 4;
    const int head = bid & 15;
    const int lane = threadIdx.x;
    __shared__ float qs[7][64], ks[7][64], vs[7][64];
    __shared__ float sc[7][8], pr[7][8];
    const long t0 = (long)win * 7;
    const ushort_t* base = qkv + t0 * 3072 + head * 64 + lane;
    #pragma unroll
    for (int i = 0; i < 7; ++i) {
        qs[i][lane] = b2f(base[(long)i * 3072]);
        ks[i][lane] = b2f(base[(long)i * 3072 + 1024]);
        vs[i][lane] = b2f(base[(long)i * 3072 + 2048]);
    }
    __syncthreads();
    if (lane < 49) {
        int i = lane / 7, j = lane % 7;
        float a = 0.f;
        #pragma unroll
        for (int d = 0; d < 64; ++d) a += qs[i][d] * ks[j][d];
        sc[i][j] = a * 0.125f;
    }
    __syncthreads();
    if (lane < 7) {
        float m = sc[lane][0];
        #pragma unroll
        for (int j = 1; j < 7; ++j) m = fmaxf(m, sc[lane][j]);
        float e[7], den = 0.f;
        #pragma unroll
        for (int j = 0; j < 7; ++j) { e[j] = __expf(sc[lane][j] - m); den += e[j]; }
        float inv = 1.f / den;
        #pragma unroll
        for (int j = 0; j < 7; ++j) pr[lane][j] = e[j] * inv;
    }
    __syncthreads();
    ushort_t* ob = o + t0 * 1024 + head * 64 + lane;
    #pragma unroll
    for (int i = 0; i < 7; ++i) {
        float a = 0.f;
        #pragma unroll
        for (int j = 0; j < 7; ++j) a += pr[i][j] * vs[j][lane];
        ob[(long)i * 1024] = f2b(a);
    }
}

// ---------------- row LayerNorm over H=1024; 256 threads, 4 elems/thread ----------------
template<typename OutT>
__global__ __launch_bounds__(256)
void ln_kernel(const ushort_t* in, OutT* out,
               const float* __restrict__ g, const float* __restrict__ b)
{
    const long row = blockIdx.x;
    const int tid = threadIdx.x;
    const ushort_t* p = in + row * H_;
    ushort4 raw = ((const ushort4*)p)[tid];
    float x0 = b2f(raw.x), x1 = b2f(raw.y), x2 = b2f(raw.z), x3 = b2f(raw.w);
    float s  = x0 + x1 + x2 + x3;
    float ss = x0*x0 + x1*x1 + x2*x2 + x3*x3;
    #pragma unroll
    for (int off = 32; off > 0; off >>= 1) {
        s  += __shfl_down(s,  off, 64);
        ss += __shfl_down(ss, off, 64);
    }
    __shared__ float rs[4], rss[4];
    const int wave = tid >> 6, lane = tid & 63;
    if (lane == 0) { rs[wave] = s; rss[wave] = ss; }
    __syncthreads();
    float S  = rs[0] + rs[1] + rs[2] + rs[3];
    float SS = rss[0] + rss[1] + rss[2] + rss[3];
    float mean = S * (1.f / 1024.f);
    float var  = SS * (1.f / 1024.f) - mean * mean;
    float inv  = rsqrtf(var + 1e-5f);
    float4 gv = ((const float4*)g)[tid];
    float4 bvv = ((const float4*)b)[tid];
    float y0 = (x0 - mean) * inv * gv.x + bvv.x;
    float y1 = (x1 - mean) * inv * gv.y + bvv.y;
    float y2 = (x2 - mean) * inv * gv.z + bvv.z;
    float y3 = (x3 - mean) * inv * gv.w + bvv.w;
    if constexpr (sizeof(OutT) == 2) {
        ushort4 ov; ov.x = f2b(y0); ov.y = f2b(y1); ov.z = f2b(y2); ov.w = f2b(y3);
        ((ushort4*)out)[row * 256 + tid] = ov;
    } else {
        float4 ov; ov.x = y0; ov.y = y1; ov.z = y2; ov.w = y3;
        ((float4*)out)[row * 256 + tid] = ov;
    }
}

// ---------------- launch ----------------
extern "C" void kernel_launch(void* const* d_in, const int* in_sizes, int n_in,
                              void* d_out, int out_size, void* d_ws, size_t ws_size,
                              hipStream_t stream)
{
    const float* x      = (const float*)d_in[0];
    const float* wqkv_f = (const float*)d_in[1];
    const float* bqkv   = (const float*)d_in[2];
    const float* wout_f = (const float*)d_in[3];
    const float* bout   = (const float*)d_in[4];
    const float* ln1g   = (const float*)d_in[5];
    const float* ln1b   = (const float*)d_in[6];
    const float* ln2g   = (const float*)d_in[7];
    const float* ln2b   = (const float*)d_in[8];
    const float* wff1_f = (const float*)d_in[9];
    const float* bff1   = (const float*)d_in[10];
    const float* wff2_f = (const float*)d_in[11];
    const float* bff2   = (const float*)d_in[12];
    float* out = (float*)d_out;

    const size_t WQKV_N = 3072l * 1024, WOUT_N = 1024l * 1024;
    const size_t WFF1_N = 4096l * 1024, WFF2_N = 1024l * 4096;
    const size_t welems = WQKV_N + WOUT_N + WFF1_N + WFF2_N;

    // chunk rows R: multiple of lcm(7,256)=1792; per-chunk arena = R*14336 B + weights
    int nc = 1;
    while (nc < 16 && (size_t)(MTOT / nc) * 14336 + welems * 2 > ws_size) nc <<= 1;
    const long R = MTOT / nc;

    char* ws = (char*)d_ws;
    ushort_t* qkv  = (ushort_t*)ws;                          // [R,3072]
    ushort_t* obuf = (ushort_t*)(ws + (size_t)R * 3072 * 2); // [R,1024]
    ushort_t* ff   = qkv;                                    // [R,4096] reuses qkv+obuf
    ushort_t* ybuf = (ushort_t*)(ws + (size_t)R * 4096 * 2); // [R,1024]
    ushort_t* s2   = (ushort_t*)(ws + (size_t)R * 5120 * 2); // [R,1024]
    ushort_t* xb   = (ushort_t*)(ws + (size_t)R * 6144 * 2); // [R,1024]
    ushort_t* wq   = (ushort_t*)(ws + (size_t)R * 7168 * 2);
    ushort_t* wo   = wq + WQKV_N;
    ushort_t* w1   = wo + WOUT_N;
    ushort_t* w2   = w1 + WFF1_N;

    f2b_kernel<<<WQKV_N / 1024, 256, 0, stream>>>(wqkv_f, wq);
    f2b_kernel<<<WOUT_N / 1024, 256, 0, stream>>>(wout_f, wo);
    f2b_kernel<<<WFF1_N / 1024, 256, 0, stream>>>(wff1_f, w1);
    f2b_kernel<<<WFF2_N / 1024, 256, 0, stream>>>(wff2_f, w2);

    for (int c = 0; c < nc; ++c) {
        const float* xc = x + (size_t)c * R * H_;
        float* oc = out + (size_t)c * R * H_;
        const int GY = R / 256;
        f2b_kernel<<<(R * H_) / 1024, 256, 0, stream>>>(xc, xb);
        // qkv = x @ Wqkv^T + b
        gemm_bt<0, float><<<12 * GY, 512, 0, stream>>>(xb, wq, bqkv, (const float*)nullptr, qkv, 3072, 1024, 12);
        // windowed attention
        attn_kernel<<<(R / 7) * 16, 64, 0, stream>>>(qkv, obuf);
        // s1 = x + o @ Wout^T + b   (residual in fp32 from original x)
        gemm_bt<2, float><<<4 * GY, 512, 0, stream>>>(obuf, wo, bout, xc, ybuf, 1024, 1024, 4);
        // y = LN1(s1), in place
        ln_kernel<ushort_t><<<R, 256, 0, stream>>>(ybuf, ybuf, ln1g, ln1b);
        // ff = relu(y @ W1^T + b1)
        gemm_bt<1, float><<<16 * GY, 512, 0, stream>>>(ybuf, w1, bff1, (const float*)nullptr, ff, 4096, 1024, 16);
        // s2 = y + ff @ W2^T + b2
        gemm_bt<2, ushort_t><<<4 * GY, 512, 0, stream>>>(ff, w2, bff2, ybuf, s2, 1024, 4096, 4);
        // out = LN2(s2), fp32
        ln_kernel<float><<<R, 256, 0, stream>>>(s2, oc, ln2g, ln2b);
    }
}

// Round 7
// 967.243 us; speedup vs baseline: 1.0282x; 1.0282x over previous
//
#include <hip/hip_runtime.h>

typedef unsigned short ushort_t;
typedef __attribute__((ext_vector_type(8))) short short8;
typedef __attribute__((ext_vector_type(4))) float f32x4;

#define MTOT 28672   // B*S = 8*3584
#define H_   1024

static __device__ __forceinline__ float b2f(ushort_t u) {
    return __uint_as_float(((unsigned)u) << 16);
}
static __device__ __forceinline__ ushort_t f2b(float f) {
    unsigned u = __float_as_uint(f);
    u += 0x7fffu + ((u >> 16) & 1u);
    return (ushort_t)(u >> 16);
}

#define GLOAD(src, dst) __builtin_amdgcn_global_load_lds( \
    (const __attribute__((address_space(1))) void*)(src), \
    (__attribute__((address_space(3))) void*)(dst), 16, 0, 0)
#define MFMA16(a, b, c) __builtin_amdgcn_mfma_f32_16x16x32_bf16(a, b, c, 0, 0, 0)
#define LGKM0_FENCE() do { \
    asm volatile("s_waitcnt lgkmcnt(0)" ::: "memory"); \
    __builtin_amdgcn_sched_barrier(0); } while (0)

// ---------------- fp32 -> bf16 conversion (n % 1024 == 0), 4 elems/thread ----------------
__global__ __launch_bounds__(256)
void f2b_kernel(const float* __restrict__ in, ushort_t* __restrict__ out)
{
    size_t i = (size_t)blockIdx.x * 256 + threadIdx.x;
    float4 v = ((const float4*)in)[i];
    ushort4 o;
    o.x = f2b(v.x); o.y = f2b(v.y); o.z = f2b(v.z); o.w = f2b(v.w);
    ((ushort4*)out)[i] = o;
}

// ---------------- bf16 GEMM v7: BM=BN=256, BK=64, 8 waves (2m x 4n, 128x64 each) -------
// m201-faithful phase schedule on the v4 memory plan.
// LDS 128 KB: lds[buf 2][region 4][16 KB]; region 0=A-Kh0, 1=B-Kh0, 2=A-Kh1, 3=B-Kh1.
// Per K64 tile t, 4 phases; phase p = { pre-barrier: ds_reads for p (data established at
// the PREVIOUS phase's barrier) + stage region p of tile t+1 (2 GLOADs) + vmcnt(4) at odd
// phases -> s_barrier -> lgkmcnt(0)+sched_barrier(0) -> setprio(1) 16 MFMA setprio(0) }.
// Residency: r0,r1(t) established at ph3(t-1) barrier; r2,r3(t) at ph1(t) barrier.
// Tail: vmcnt(0) at ph1 of last tile. Conflict-free chunk layout pos = kk ^ ((r>>1)&3).
// Swapped-operand MFMA: lane (fr,kg) of frag (m,n) holds row wm*128+m*16+fr,
// cols wn*64+n*16+kg*4+{0..3}; epilogue transposes via swizzled LDS -> 64B stores.
template<int EPI, typename ResT>
__global__ __launch_bounds__(512, 1)
void gemm_bt(const ushort_t* __restrict__ A, const ushort_t* __restrict__ Bt,
             const float* __restrict__ bias, const ResT* __restrict__ Res,
             ushort_t* __restrict__ C, int N, int K, int GX)
{
    __shared__ __align__(16) ushort_t lds[2][4][8192];   // 128 KB
    const int tid  = threadIdx.x;
    const int wave = tid >> 6;
    const int lane = tid & 63;
    const int wm = wave >> 2, wn = wave & 3;   // 2x4 waves, each 128 rows x 64 cols
    const int fr = lane & 15, kg = lane >> 4;

    // bijective XCD-chunked swizzle (m204 form)
    const int nwg = gridDim.x;
    const int xcd = blockIdx.x & 7, ofs = blockIdx.x >> 3;
    const int q8 = nwg >> 3, r8 = nwg & 7;
    const int wg = (xcd < r8 ? xcd * (q8 + 1) : r8 * (q8 + 1) + (xcd - r8) * q8) + ofs;
    const long row0 = (long)(wg / GX) * 256;
    const long col0 = (long)(wg % GX) * 256;

    const int NT = K >> 6;

    // ---- staging: per region 1024 chunks = 512 threads x 2 rounds (round1 = +128 rows) ----
    const int sr_ = tid >> 2;
    const int kk_ = (tid & 3) ^ ((sr_ >> 1) & 3);
    const ushort_t* pa = A  + (row0 + sr_) * (size_t)K + kk_ * 8;
    const ushort_t* pb = Bt + (col0 + sr_) * (size_t)K + kk_ * 8;
    const size_t rstep = (size_t)128 * K;

    // prologue: tile 0, regions in strict order 0,1,2,3; establish r0,r1 before loop
    {
        ushort_t* d0 = &lds[0][0][0] + wave * 512;
        ushort_t* d1 = &lds[0][1][0] + wave * 512;
        ushort_t* d2 = &lds[0][2][0] + wave * 512;
        ushort_t* d3 = &lds[0][3][0] + wave * 512;
        GLOAD(pa,            d0); GLOAD(pa + rstep,      d0 + 4096);
        GLOAD(pb,            d1); GLOAD(pb + rstep,      d1 + 4096);
        GLOAD(pa + 32,       d2); GLOAD(pa + 32 + rstep, d2 + 4096);
        GLOAD(pb + 32,       d3); GLOAD(pb + 32 + rstep, d3 + 4096);
    }
    asm volatile("s_waitcnt vmcnt(4)" ::: "memory");
    asm volatile("s_barrier" ::: "memory");

    // per-lane ds_read byte offsets
    const int pos2  = kg ^ ((fr >> 1) & 3);
    const int abase = (wm * 128 + fr) * 64 + pos2 * 16;   // + m*1024
    const int bbase = (wn * 64  + fr) * 64 + pos2 * 16;   // + n*1024

    f32x4 acc[8][4] = {};

    for (int t = 0; t < NT; ++t) {
        const int b = t & 1;
        const bool pf = (t + 1 < NT);
        const size_t go = (size_t)(t + 1) * 64;
        const char* rA0 = (const char*)&lds[b][0][0];
        const char* rB0 = (const char*)&lds[b][1][0];
        const char* rA1 = (const char*)&lds[b][2][0];
        const char* rB1 = (const char*)&lds[b][3][0];
        ushort_t* d0 = &lds[1 - b][0][0] + wave * 512;
        ushort_t* d1 = &lds[1 - b][1][0] + wave * 512;
        ushort_t* d2 = &lds[1 - b][2][0] + wave * 512;
        ushort_t* d3 = &lds[1 - b][3][0] + wave * 512;

        short8 bv[4], avlo[4], avhi[4];

        // ===== phase 0: reads r0,r1 (established at ph3(t-1)); stage r0(t+1) =====
        #pragma unroll
        for (int j = 0; j < 4; ++j) bv[j]   = *(const short8*)(rB0 + bbase + j * 1024);
        #pragma unroll
        for (int i = 0; i < 4; ++i) avlo[i] = *(const short8*)(rA0 + abase + i * 1024);
        if (pf) { GLOAD(pa + go, d0); GLOAD(pa + go + rstep, d0 + 4096); }
        asm volatile("s_barrier" ::: "memory");
        LGKM0_FENCE();
        __builtin_amdgcn_s_setprio(1);
        #pragma unroll
        for (int i = 0; i < 4; ++i)
            #pragma unroll
            for (int j = 0; j < 4; ++j) acc[i][j] = MFMA16(bv[j], avlo[i], acc[i][j]);
        __builtin_amdgcn_s_setprio(0);

        // ===== phase 1: reads r0 hi; stage r1(t+1); vmcnt -> r2,r3(t) resident =====
        #pragma unroll
        for (int i = 0; i < 4; ++i) avhi[i] = *(const short8*)(rA0 + abase + (4 + i) * 1024);
        if (pf) { GLOAD(pb + go, d1); GLOAD(pb + go + rstep, d1 + 4096); }
        if (pf) { asm volatile("s_waitcnt vmcnt(4)" ::: "memory"); }
        else    { asm volatile("s_waitcnt vmcnt(0)" ::: "memory"); }
        asm volatile("s_barrier" ::: "memory");
        LGKM0_FENCE();
        __builtin_amdgcn_s_setprio(1);
        #pragma unroll
        for (int i = 0; i < 4; ++i)
            #pragma unroll
            for (int j = 0; j < 4; ++j) acc[4 + i][j] = MFMA16(bv[j], avhi[i], acc[4 + i][j]);
        __builtin_amdgcn_s_setprio(0);

        // ===== phase 2: reads r2,r3 (established at ph1); stage r2(t+1) =====
        #pragma unroll
        for (int j = 0; j < 4; ++j) bv[j]   = *(const short8*)(rB1 + bbase + j * 1024);
        #pragma unroll
        for (int i = 0; i < 4; ++i) avlo[i] = *(const short8*)(rA1 + abase + i * 1024);
        if (pf) { GLOAD(pa + go + 32, d2); GLOAD(pa + go + 32 + rstep, d2 + 4096); }
        asm volatile("s_barrier" ::: "memory");
        LGKM0_FENCE();
        __builtin_amdgcn_s_setprio(1);
        #pragma unroll
        for (int i = 0; i < 4; ++i)
            #pragma unroll
            for (int j = 0; j < 4; ++j) acc[i][j] = MFMA16(bv[j], avlo[i], acc[i][j]);
        __builtin_amdgcn_s_setprio(0);

        // ===== phase 3: reads r2 hi; stage r3(t+1); vmcnt -> r0,r1(t+1) resident =====
        #pragma unroll
        for (int i = 0; i < 4; ++i) avhi[i] = *(const short8*)(rA1 + abase + (4 + i) * 1024);
        if (pf) { GLOAD(pb + go + 32, d3); GLOAD(pb + go + 32 + rstep, d3 + 4096); }
        if (pf) { asm volatile("s_waitcnt vmcnt(4)" ::: "memory"); }
        asm volatile("s_barrier" ::: "memory");
        LGKM0_FENCE();
        __builtin_amdgcn_s_setprio(1);
        #pragma unroll
        for (int i = 0; i < 4; ++i)
            #pragma unroll
            for (int j = 0; j < 4; ++j) acc[4 + i][j] = MFMA16(bv[j], avhi[i], acc[4 + i][j]);
        __builtin_amdgcn_s_setprio(0);
    }

    // ---- epilogue: swapped layout -> swizzled LDS bf16 tile -> coalesced stores ----
    __syncthreads();   // all K-loop LDS reads complete before overwrite
    char* L = (char*)&lds[0][0][0];   // [256 rows][512 B], chunk16 ^= (row&31)

    // bias per lane: 4 consecutive cols per n-frag
    float4 bias4[4];
    #pragma unroll
    for (int n = 0; n < 4; ++n)
        bias4[n] = *(const float4*)&bias[col0 + wn * 64 + n * 16 + kg * 4];

    #pragma unroll
    for (int m = 0; m < 8; ++m) {
        const int row_t = wm * 128 + m * 16 + fr;
        const long grow = (row0 + row_t) * (long)N;
        #pragma unroll
        for (int n = 0; n < 4; ++n) {
            const int colr = wn * 64 + n * 16 + kg * 4;     // col within tile
            float v0 = acc[m][n][0] + bias4[n].x;
            float v1 = acc[m][n][1] + bias4[n].y;
            float v2 = acc[m][n][2] + bias4[n].z;
            float v3 = acc[m][n][3] + bias4[n].w;
            if constexpr (EPI == 1) {
                v0 = fmaxf(v0, 0.f); v1 = fmaxf(v1, 0.f);
                v2 = fmaxf(v2, 0.f); v3 = fmaxf(v3, 0.f);
            }
            if constexpr (EPI == 2) {
                if constexpr (sizeof(ResT) == 4) {
                    float4 r4 = *(const float4*)&Res[grow + col0 + colr];
                    v0 += r4.x; v1 += r4.y; v2 += r4.z; v3 += r4.w;
                } else {
                    ushort4 r4 = *(const ushort4*)&Res[grow + col0 + colr];
                    v0 += b2f(r4.x); v1 += b2f(r4.y); v2 += b2f(r4.z); v3 += b2f(r4.w);
                }
            }
            ushort4 pk; pk.x = f2b(v0); pk.y = f2b(v1); pk.z = f2b(v2); pk.w = f2b(v3);
            const int cbyte = colr * 2;                      // 0..510
            const int chunk = cbyte >> 4;                    // 0..31
            const int addr  = row_t * 512 + ((chunk ^ (row_t & 31)) << 4) + (cbyte & 15);
            *(ushort4*)(L + addr) = pk;
        }
    }
    __syncthreads();

    // readback: 4 lanes per row -> 64B contiguous store segments
    #pragma unroll
    for (int p = 0; p < 2; ++p) {
        const int row_t = p * 128 + (tid >> 2);
        const long grow = (row0 + row_t) * (long)N + col0;
        #pragma unroll
        for (int k = 0; k < 8; ++k) {
            const int chunk = k * 4 + (tid & 3);
            short8 d = *(const short8*)(L + row_t * 512 + ((chunk ^ (row_t & 31)) << 4));
            *(short8*)&C[grow + chunk * 8] = d;
        }
    }
}

// ---------------- per-(window,head) attention: q,k,v [7,64]; one wave per block ----------------
__global__ __launch_bounds__(64)
void attn_kernel(const ushort_t* __restrict__ qkv, ushort_t* __restrict__ o)
{
    const int bid  = blockIdx.x;
    const int win  = bid >> 4;
    const int head = bid & 15;
    const int lane = threadIdx.x;
    __shared__ float qs[7][64], ks[7][64], vs[7][64];
    __shared__ float sc[7][8], pr[7][8];
    const long t0 = (long)win * 7;
    const ushort_t* base = qkv + t0 * 3072 + head * 64 + lane;
    #pragma unroll
    for (int i = 0; i < 7; ++i) {
        qs[i][lane] = b2f(base[(long)i * 3072]);
        ks[i][lane] = b2f(base[(long)i * 3072 + 1024]);
        vs[i][lane] = b2f(base[(long)i * 3072 + 2048]);
    }
    __syncthreads();
    if (lane < 49) {
        int i = lane / 7, j = lane % 7;
        float a = 0.f;
        #pragma unroll
        for (int d = 0; d < 64; ++d) a += qs[i][d] * ks[j][d];
        sc[i][j] = a * 0.125f;
    }
    __syncthreads();
    if (lane < 7) {
        float m = sc[lane][0];
        #pragma unroll
        for (int j = 1; j < 7; ++j) m = fmaxf(m, sc[lane][j]);
        float e[7], den = 0.f;
        #pragma unroll
        for (int j = 0; j < 7; ++j) { e[j] = __expf(sc[lane][j] - m); den += e[j]; }
        float inv = 1.f / den;
        #pragma unroll
        for (int j = 0; j < 7; ++j) pr[lane][j] = e[j] * inv;
    }
    __syncthreads();
    ushort_t* ob = o + t0 * 1024 + head * 64 + lane;
    #pragma unroll
    for (int i = 0; i < 7; ++i) {
        float a = 0.f;
        #pragma unroll
        for (int j = 0; j < 7; ++j) a += pr[i][j] * vs[j][lane];
        ob[(long)i * 1024] = f2b(a);
    }
}

// ---------------- row LayerNorm over H=1024; 256 threads, 4 elems/thread ----------------
template<typename OutT>
__global__ __launch_bounds__(256)
void ln_kernel(const ushort_t* in, OutT* out,
               const float* __restrict__ g, const float* __restrict__ b)
{
    const long row = blockIdx.x;
    const int tid = threadIdx.x;
    const ushort_t* p = in + row * H_;
    ushort4 raw = ((const ushort4*)p)[tid];
    float x0 = b2f(raw.x), x1 = b2f(raw.y), x2 = b2f(raw.z), x3 = b2f(raw.w);
    float s  = x0 + x1 + x2 + x3;
    float ss = x0*x0 + x1*x1 + x2*x2 + x3*x3;
    #pragma unroll
    for (int off = 32; off > 0; off >>= 1) {
        s  += __shfl_down(s,  off, 64);
        ss += __shfl_down(ss, off, 64);
    }
    __shared__ float rs[4], rss[4];
    const int wave = tid >> 6, lane = tid & 63;
    if (lane == 0) { rs[wave] = s; rss[wave] = ss; }
    __syncthreads();
    float S  = rs[0] + rs[1] + rs[2] + rs[3];
    float SS = rss[0] + rss[1] + rss[2] + rss[3];
    float mean = S * (1.f / 1024.f);
    float var  = SS * (1.f / 1024.f) - mean * mean;
    float inv  = rsqrtf(var + 1e-5f);
    float4 gv = ((const float4*)g)[tid];
    float4 bvv = ((const float4*)b)[tid];
    float y0 = (x0 - mean) * inv * gv.x + bvv.x;
    float y1 = (x1 - mean) * inv * gv.y + bvv.y;
    float y2 = (x2 - mean) * inv * gv.z + bvv.z;
    float y3 = (x3 - mean) * inv * gv.w + bvv.w;
    if constexpr (sizeof(OutT) == 2) {
        ushort4 ov; ov.x = f2b(y0); ov.y = f2b(y1); ov.z = f2b(y2); ov.w = f2b(y3);
        ((ushort4*)out)[row * 256 + tid] = ov;
    } else {
        float4 ov; ov.x = y0; ov.y = y1; ov.z = y2; ov.w = y3;
        ((float4*)out)[row * 256 + tid] = ov;
    }
}

// ---------------- launch ----------------
extern "C" void kernel_launch(void* const* d_in, const int* in_sizes, int n_in,
                              void* d_out, int out_size, void* d_ws, size_t ws_size,
                              hipStream_t stream)
{
    const float* x      = (const float*)d_in[0];
    const float* wqkv_f = (const float*)d_in[1];
    const float* bqkv   = (const float*)d_in[2];
    const float* wout_f = (const float*)d_in[3];
    const float* bout   = (const float*)d_in[4];
    const float* ln1g   = (const float*)d_in[5];
    const float* ln1b   = (const float*)d_in[6];
    const float* ln2g   = (const float*)d_in[7];
    const float* ln2b   = (const float*)d_in[8];
    const float* wff1_f = (const float*)d_in[9];
    const float* bff1   = (const float*)d_in[10];
    const float* wff2_f = (const float*)d_in[11];
    const float* bff2   = (const float*)d_in[12];
    float* out = (float*)d_out;

    const size_t WQKV_N = 3072l * 1024, WOUT_N = 1024l * 1024;
    const size_t WFF1_N = 4096l * 1024, WFF2_N = 1024l * 4096;
    const size_t welems = WQKV_N + WOUT_N + WFF1_N + WFF2_N;

    // chunk rows R: multiple of lcm(7,256)=1792; per-chunk arena = R*14336 B + weights
    int nc = 1;
    while (nc < 16 && (size_t)(MTOT / nc) * 14336 + welems * 2 > ws_size) nc <<= 1;
    const long R = MTOT / nc;

    char* ws = (char*)d_ws;
    ushort_t* qkv  = (ushort_t*)ws;                          // [R,3072]
    ushort_t* obuf = (ushort_t*)(ws + (size_t)R * 3072 * 2); // [R,1024]
    ushort_t* ff   = qkv;                                    // [R,4096] reuses qkv+obuf
    ushort_t* ybuf = (ushort_t*)(ws + (size_t)R * 4096 * 2); // [R,1024]
    ushort_t* s2   = (ushort_t*)(ws + (size_t)R * 5120 * 2); // [R,1024]
    ushort_t* xb   = (ushort_t*)(ws + (size_t)R * 6144 * 2); // [R,1024]
    ushort_t* wq   = (ushort_t*)(ws + (size_t)R * 7168 * 2);
    ushort_t* wo   = wq + WQKV_N;
    ushort_t* w1   = wo + WOUT_N;
    ushort_t* w2   = w1 + WFF1_N;

    f2b_kernel<<<WQKV_N / 1024, 256, 0, stream>>>(wqkv_f, wq);
    f2b_kernel<<<WOUT_N / 1024, 256, 0, stream>>>(wout_f, wo);
    f2b_kernel<<<WFF1_N / 1024, 256, 0, stream>>>(wff1_f, w1);
    f2b_kernel<<<WFF2_N / 1024, 256, 0, stream>>>(wff2_f, w2);

    for (int c = 0; c < nc; ++c) {
        const float* xc = x + (size_t)c * R * H_;
        float* oc = out + (size_t)c * R * H_;
        const int GY = R / 256;
        f2b_kernel<<<(R * H_) / 1024, 256, 0, stream>>>(xc, xb);
        // qkv = x @ Wqkv^T + b
        gemm_bt<0, float><<<12 * GY, 512, 0, stream>>>(xb, wq, bqkv, (const float*)nullptr, qkv, 3072, 1024, 12);
        // windowed attention
        attn_kernel<<<(R / 7) * 16, 64, 0, stream>>>(qkv, obuf);
        // s1 = x + o @ Wout^T + b   (residual in fp32 from original x)
        gemm_bt<2, float><<<4 * GY, 512, 0, stream>>>(obuf, wo, bout, xc, ybuf, 1024, 1024, 4);
        // y = LN1(s1), in place
        ln_kernel<ushort_t><<<R, 256, 0, stream>>>(ybuf, ybuf, ln1g, ln1b);
        // ff = relu(y @ W1^T + b1)
        gemm_bt<1, float><<<16 * GY, 512, 0, stream>>>(ybuf, w1, bff1, (const float*)nullptr, ff, 4096, 1024, 16);
        // s2 = y + ff @ W2^T + b2
        gemm_bt<2, ushort_t><<<4 * GY, 512, 0, stream>>>(ff, w2, bff2, ybuf, s2, 1024, 4096, 4);
        // out = LN2(s2), fp32
        ln_kernel<float><<<R, 256, 0, stream>>>(s2, oc, ln2g, ln2b);
    }
}

// Round 9
// 963.160 us; speedup vs baseline: 1.0326x; 1.0042x over previous
//
#include <hip/hip_runtime.h>

typedef unsigned short ushort_t;
typedef __attribute__((ext_vector_type(8))) short short8;
typedef __attribute__((ext_vector_type(4))) float f32x4;

#define MTOT 28672   // B*S = 8*3584
#define H_   1024

static __device__ __forceinline__ float b2f(ushort_t u) {
    return __uint_as_float(((unsigned)u) << 16);
}
static __device__ __forceinline__ ushort_t f2b(float f) {
    unsigned u = __float_as_uint(f);
    u += 0x7fffu + ((u >> 16) & 1u);
    return (ushort_t)(u >> 16);
}

#define GLOAD(src, dst) __builtin_amdgcn_global_load_lds( \
    (const __attribute__((address_space(1))) void*)(src), \
    (__attribute__((address_space(3))) void*)(dst), 16, 0, 0)
#define MFMA16(a, b, c) __builtin_amdgcn_mfma_f32_16x16x32_bf16(a, b, c, 0, 0, 0)
#define LGKM0_FENCE() do { \
    asm volatile("s_waitcnt lgkmcnt(0)" ::: "memory"); \
    __builtin_amdgcn_sched_barrier(0); } while (0)

// ---------------- fp32 -> bf16 conversion (n % 1024 == 0), 4 elems/thread ----------------
__global__ __launch_bounds__(256)
void f2b_kernel(const float* __restrict__ in, ushort_t* __restrict__ out)
{
    size_t i = (size_t)blockIdx.x * 256 + threadIdx.x;
    float4 v = ((const float4*)in)[i];
    ushort4 o;
    o.x = f2b(v.x); o.y = f2b(v.y); o.z = f2b(v.z); o.w = f2b(v.w);
    ((ushort4*)out)[i] = o;
}

// ---------------- merged weight conversion: 4 segments, one launch ----------------
// sizes (float4 units): wqkv 786432, wout 262144, wff1 1048576, wff2 1048576 -> 3145728
__global__ __launch_bounds__(256)
void f2b4_kernel(const float* __restrict__ s0, ushort_t* __restrict__ d0,
                 const float* __restrict__ s1, ushort_t* __restrict__ d1,
                 const float* __restrict__ s2, ushort_t* __restrict__ d2,
                 const float* __restrict__ s3, ushort_t* __restrict__ d3)
{
    size_t i = (size_t)blockIdx.x * 256 + threadIdx.x;   // grid = 12288 blocks exactly
    const float* s; ushort_t* d; size_t off;
    if (i < 786432)            { s = s0; d = d0; off = i; }
    else if (i < 1048576)      { s = s1; d = d1; off = i - 786432; }
    else if (i < 2097152)      { s = s2; d = d2; off = i - 1048576; }
    else                       { s = s3; d = d3; off = i - 2097152; }
    float4 v = ((const float4*)s)[off];
    ushort4 o;
    o.x = f2b(v.x); o.y = f2b(v.y); o.z = f2b(v.z); o.w = f2b(v.w);
    ((ushort4*)d)[off] = o;
}

// ---------------- bf16 GEMM v7: BM=BN=256, BK=64, 8 waves (2m x 4n, 128x64 each) -------
// Frozen from R7 (best-of-family: v4/v5/v6/v7 all 39-43% MfmaUtil; LDS-BW ceiling ~61%,
// K=1024 amortization eats the rest). See R7 comments for schedule proof.
template<int EPI, typename ResT>
__global__ __launch_bounds__(512, 1)
void gemm_bt(const ushort_t* __restrict__ A, const ushort_t* __restrict__ Bt,
             const float* __restrict__ bias, const ResT* __restrict__ Res,
             ushort_t* __restrict__ C, int N, int K, int GX)
{
    __shared__ __align__(16) ushort_t lds[2][4][8192];   // 128 KB
    const int tid  = threadIdx.x;
    const int wave = tid >> 6;
    const int lane = tid & 63;
    const int wm = wave >> 2, wn = wave & 3;   // 2x4 waves, each 128 rows x 64 cols
    const int fr = lane & 15, kg = lane >> 4;

    // bijective XCD-chunked swizzle (m204 form)
    const int nwg = gridDim.x;
    const int xcd = blockIdx.x & 7, ofs = blockIdx.x >> 3;
    const int q8 = nwg >> 3, r8 = nwg & 7;
    const int wg = (xcd < r8 ? xcd * (q8 + 1) : r8 * (q8 + 1) + (xcd - r8) * q8) + ofs;
    const long row0 = (long)(wg / GX) * 256;
    const long col0 = (long)(wg % GX) * 256;

    const int NT = K >> 6;

    // ---- staging: per region 1024 chunks = 512 threads x 2 rounds (round1 = +128 rows) ----
    const int sr_ = tid >> 2;
    const int kk_ = (tid & 3) ^ ((sr_ >> 1) & 3);
    const ushort_t* pa = A  + (row0 + sr_) * (size_t)K + kk_ * 8;
    const ushort_t* pb = Bt + (col0 + sr_) * (size_t)K + kk_ * 8;
    const size_t rstep = (size_t)128 * K;

    // prologue: tile 0, regions in strict order 0,1,2,3; establish r0,r1 before loop
    {
        ushort_t* d0 = &lds[0][0][0] + wave * 512;
        ushort_t* d1 = &lds[0][1][0] + wave * 512;
        ushort_t* d2 = &lds[0][2][0] + wave * 512;
        ushort_t* d3 = &lds[0][3][0] + wave * 512;
        GLOAD(pa,            d0); GLOAD(pa + rstep,      d0 + 4096);
        GLOAD(pb,            d1); GLOAD(pb + rstep,      d1 + 4096);
        GLOAD(pa + 32,       d2); GLOAD(pa + 32 + rstep, d2 + 4096);
        GLOAD(pb + 32,       d3); GLOAD(pb + 32 + rstep, d3 + 4096);
    }
    asm volatile("s_waitcnt vmcnt(4)" ::: "memory");
    asm volatile("s_barrier" ::: "memory");

    // per-lane ds_read byte offsets
    const int pos2  = kg ^ ((fr >> 1) & 3);
    const int abase = (wm * 128 + fr) * 64 + pos2 * 16;   // + m*1024
    const int bbase = (wn * 64  + fr) * 64 + pos2 * 16;   // + n*1024

    f32x4 acc[8][4] = {};

    for (int t = 0; t < NT; ++t) {
        const int b = t & 1;
        const bool pf = (t + 1 < NT);
        const size_t go = (size_t)(t + 1) * 64;
        const char* rA0 = (const char*)&lds[b][0][0];
        const char* rB0 = (const char*)&lds[b][1][0];
        const char* rA1 = (const char*)&lds[b][2][0];
        const char* rB1 = (const char*)&lds[b][3][0];
        ushort_t* d0 = &lds[1 - b][0][0] + wave * 512;
        ushort_t* d1 = &lds[1 - b][1][0] + wave * 512;
        ushort_t* d2 = &lds[1 - b][2][0] + wave * 512;
        ushort_t* d3 = &lds[1 - b][3][0] + wave * 512;

        short8 bv[4], avlo[4], avhi[4];

        // ===== phase 0 =====
        #pragma unroll
        for (int j = 0; j < 4; ++j) bv[j]   = *(const short8*)(rB0 + bbase + j * 1024);
        #pragma unroll
        for (int i = 0; i < 4; ++i) avlo[i] = *(const short8*)(rA0 + abase + i * 1024);
        if (pf) { GLOAD(pa + go, d0); GLOAD(pa + go + rstep, d0 + 4096); }
        asm volatile("s_barrier" ::: "memory");
        LGKM0_FENCE();
        __builtin_amdgcn_s_setprio(1);
        #pragma unroll
        for (int i = 0; i < 4; ++i)
            #pragma unroll
            for (int j = 0; j < 4; ++j) acc[i][j] = MFMA16(bv[j], avlo[i], acc[i][j]);
        __builtin_amdgcn_s_setprio(0);

        // ===== phase 1 =====
        #pragma unroll
        for (int i = 0; i < 4; ++i) avhi[i] = *(const short8*)(rA0 + abase + (4 + i) * 1024);
        if (pf) { GLOAD(pb + go, d1); GLOAD(pb + go + rstep, d1 + 4096); }
        if (pf) { asm volatile("s_waitcnt vmcnt(4)" ::: "memory"); }
        else    { asm volatile("s_waitcnt vmcnt(0)" ::: "memory"); }
        asm volatile("s_barrier" ::: "memory");
        LGKM0_FENCE();
        __builtin_amdgcn_s_setprio(1);
        #pragma unroll
        for (int i = 0; i < 4; ++i)
            #pragma unroll
            for (int j = 0; j < 4; ++j) acc[4 + i][j] = MFMA16(bv[j], avhi[i], acc[4 + i][j]);
        __builtin_amdgcn_s_setprio(0);

        // ===== phase 2 =====
        #pragma unroll
        for (int j = 0; j < 4; ++j) bv[j]   = *(const short8*)(rB1 + bbase + j * 1024);
        #pragma unroll
        for (int i = 0; i < 4; ++i) avlo[i] = *(const short8*)(rA1 + abase + i * 1024);
        if (pf) { GLOAD(pa + go + 32, d2); GLOAD(pa + go + 32 + rstep, d2 + 4096); }
        asm volatile("s_barrier" ::: "memory");
        LGKM0_FENCE();
        __builtin_amdgcn_s_setprio(1);
        #pragma unroll
        for (int i = 0; i < 4; ++i)
            #pragma unroll
            for (int j = 0; j < 4; ++j) acc[i][j] = MFMA16(bv[j], avlo[i], acc[i][j]);
        __builtin_amdgcn_s_setprio(0);

        // ===== phase 3 =====
        #pragma unroll
        for (int i = 0; i < 4; ++i) avhi[i] = *(const short8*)(rA1 + abase + (4 + i) * 1024);
        if (pf) { GLOAD(pb + go + 32, d3); GLOAD(pb + go + 32 + rstep, d3 + 4096); }
        if (pf) { asm volatile("s_waitcnt vmcnt(4)" ::: "memory"); }
        asm volatile("s_barrier" ::: "memory");
        LGKM0_FENCE();
        __builtin_amdgcn_s_setprio(1);
        #pragma unroll
        for (int i = 0; i < 4; ++i)
            #pragma unroll
            for (int j = 0; j < 4; ++j) acc[4 + i][j] = MFMA16(bv[j], avhi[i], acc[4 + i][j]);
        __builtin_amdgcn_s_setprio(0);
    }

    // ---- epilogue: swapped layout -> swizzled LDS bf16 tile -> coalesced stores ----
    __syncthreads();
    char* L = (char*)&lds[0][0][0];   // [256 rows][512 B], chunk16 ^= (row&31)

    float4 bias4[4];
    #pragma unroll
    for (int n = 0; n < 4; ++n)
        bias4[n] = *(const float4*)&bias[col0 + wn * 64 + n * 16 + kg * 4];

    #pragma unroll
    for (int m = 0; m < 8; ++m) {
        const int row_t = wm * 128 + m * 16 + fr;
        const long grow = (row0 + row_t) * (long)N;
        #pragma unroll
        for (int n = 0; n < 4; ++n) {
            const int colr = wn * 64 + n * 16 + kg * 4;
            float v0 = acc[m][n][0] + bias4[n].x;
            float v1 = acc[m][n][1] + bias4[n].y;
            float v2 = acc[m][n][2] + bias4[n].z;
            float v3 = acc[m][n][3] + bias4[n].w;
            if constexpr (EPI == 1) {
                v0 = fmaxf(v0, 0.f); v1 = fmaxf(v1, 0.f);
                v2 = fmaxf(v2, 0.f); v3 = fmaxf(v3, 0.f);
            }
            if constexpr (EPI == 2) {
                if constexpr (sizeof(ResT) == 4) {
                    float4 r4 = *(const float4*)&Res[grow + col0 + colr];
                    v0 += r4.x; v1 += r4.y; v2 += r4.z; v3 += r4.w;
                } else {
                    ushort4 r4 = *(const ushort4*)&Res[grow + col0 + colr];
                    v0 += b2f(r4.x); v1 += b2f(r4.y); v2 += b2f(r4.z); v3 += b2f(r4.w);
                }
            }
            ushort4 pk; pk.x = f2b(v0); pk.y = f2b(v1); pk.z = f2b(v2); pk.w = f2b(v3);
            const int cbyte = colr * 2;
            const int chunk = cbyte >> 4;
            const int addr  = row_t * 512 + ((chunk ^ (row_t & 31)) << 4) + (cbyte & 15);
            *(ushort4*)(L + addr) = pk;
        }
    }
    __syncthreads();

    #pragma unroll
    for (int p = 0; p < 2; ++p) {
        const int row_t = p * 128 + (tid >> 2);
        const long grow = (row0 + row_t) * (long)N + col0;
        #pragma unroll
        for (int k = 0; k < 8; ++k) {
            const int chunk = k * 4 + (tid & 3);
            short8 d = *(const short8*)(L + row_t * 512 + ((chunk ^ (row_t & 31)) << 4));
            *(short8*)&C[grow + chunk * 8] = d;
        }
    }
}

// ---------------- per-(window,head) attention: q,k,v [7,64]; one wave per block --------
// R9: vectorized staging into a single contiguous LDS array (no LDS pointer array --
// addrspacecast-in-initializer is unsupported). 168 x 16B chunks over 64 lanes, 3 rounds.
__global__ __launch_bounds__(64)
void attn_kernel(const ushort_t* __restrict__ qkv, ushort_t* __restrict__ o)
{
    const int bid  = blockIdx.x;
    const int win  = bid >> 4;
    const int head = bid & 15;
    const int lane = threadIdx.x;
    __shared__ float qkvs[3 * 7 * 64];   // [mat][row][64]
    __shared__ float sc[7][8], pr[7][8];
    const long t0 = (long)win * 7;
    const ushort_t* base = qkv + t0 * 3072 + head * 64;
    #pragma unroll
    for (int r = 0; r < 3; ++r) {
        int idx = r * 64 + lane;          // 0..167 valid
        if (idx < 168) {
            int mat = idx / 56;           // 0=q, 1=k, 2=v
            int rem = idx % 56;
            int row = rem >> 3;           // 0..6
            int c8  = rem & 7;            // 0..7
            short8 v = *(const short8*)(base + mat * 1024 + (long)row * 3072 + c8 * 8);
            float* dst = &qkvs[mat * 448 + row * 64 + c8 * 8];
            #pragma unroll
            for (int e = 0; e < 8; ++e) dst[e] = b2f((ushort_t)v[e]);
        }
    }
    __syncthreads();
    const float* qs = &qkvs[0];
    const float* ks = &qkvs[448];
    const float* vs = &qkvs[896];
    if (lane < 49) {
        int i = lane / 7, j = lane % 7;
        float a = 0.f;
        #pragma unroll
        for (int d = 0; d < 64; ++d) a += qs[i * 64 + d] * ks[j * 64 + d];
        sc[i][j] = a * 0.125f;
    }
    __syncthreads();
    if (lane < 7) {
        float m = sc[lane][0];
        #pragma unroll
        for (int j = 1; j < 7; ++j) m = fmaxf(m, sc[lane][j]);
        float e[7], den = 0.f;
        #pragma unroll
        for (int j = 0; j < 7; ++j) { e[j] = __expf(sc[lane][j] - m); den += e[j]; }
        float inv = 1.f / den;
        #pragma unroll
        for (int j = 0; j < 7; ++j) pr[lane][j] = e[j] * inv;
    }
    __syncthreads();
    ushort_t* ob = o + t0 * 1024 + head * 64 + lane;
    #pragma unroll
    for (int i = 0; i < 7; ++i) {
        float a = 0.f;
        #pragma unroll
        for (int j = 0; j < 7; ++j) a += pr[i][j] * vs[j * 64 + lane];
        ob[(long)i * 1024] = f2b(a);
    }
}

// ---------------- row LayerNorm over H=1024; 256 threads, 4 elems/thread ----------------
template<typename OutT>
__global__ __launch_bounds__(256)
void ln_kernel(const ushort_t* in, OutT* out,
               const float* __restrict__ g, const float* __restrict__ b)
{
    const long row = blockIdx.x;
    const int tid = threadIdx.x;
    const ushort_t* p = in + row * H_;
    ushort4 raw = ((const ushort4*)p)[tid];
    float x0 = b2f(raw.x), x1 = b2f(raw.y), x2 = b2f(raw.z), x3 = b2f(raw.w);
    float s  = x0 + x1 + x2 + x3;
    float ss = x0*x0 + x1*x1 + x2*x2 + x3*x3;
    #pragma unroll
    for (int off = 32; off > 0; off >>= 1) {
        s  += __shfl_down(s,  off, 64);
        ss += __shfl_down(ss, off, 64);
    }
    __shared__ float rs[4], rss[4];
    const int wave = tid >> 6, lane = tid & 63;
    if (lane == 0) { rs[wave] = s; rss[wave] = ss; }
    __syncthreads();
    float S  = rs[0] + rs[1] + rs[2] + rs[3];
    float SS = rss[0] + rss[1] + rss[2] + rss[3];
    float mean = S * (1.f / 1024.f);
    float var  = SS * (1.f / 1024.f) - mean * mean;
    float inv  = rsqrtf(var + 1e-5f);
    float4 gv = ((const float4*)g)[tid];
    float4 bvv = ((const float4*)b)[tid];
    float y0 = (x0 - mean) * inv * gv.x + bvv.x;
    float y1 = (x1 - mean) * inv * gv.y + bvv.y;
    float y2 = (x2 - mean) * inv * gv.z + bvv.z;
    float y3 = (x3 - mean) * inv * gv.w + bvv.w;
    if constexpr (sizeof(OutT) == 2) {
        ushort4 ov; ov.x = f2b(y0); ov.y = f2b(y1); ov.z = f2b(y2); ov.w = f2b(y3);
        ((ushort4*)out)[row * 256 + tid] = ov;
    } else {
        float4 ov; ov.x = y0; ov.y = y1; ov.z = y2; ov.w = y3;
        ((float4*)out)[row * 256 + tid] = ov;
    }
}

// ---------------- launch ----------------
extern "C" void kernel_launch(void* const* d_in, const int* in_sizes, int n_in,
                              void* d_out, int out_size, void* d_ws, size_t ws_size,
                              hipStream_t stream)
{
    const float* x      = (const float*)d_in[0];
    const float* wqkv_f = (const float*)d_in[1];
    const float* bqkv   = (const float*)d_in[2];
    const float* wout_f = (const float*)d_in[3];
    const float* bout   = (const float*)d_in[4];
    const float* ln1g   = (const float*)d_in[5];
    const float* ln1b   = (const float*)d_in[6];
    const float* ln2g   = (const float*)d_in[7];
    const float* ln2b   = (const float*)d_in[8];
    const float* wff1_f = (const float*)d_in[9];
    const float* bff1   = (const float*)d_in[10];
    const float* wff2_f = (const float*)d_in[11];
    const float* bff2   = (const float*)d_in[12];
    float* out = (float*)d_out;

    const size_t WQKV_N = 3072l * 1024, WOUT_N = 1024l * 1024;
    const size_t WFF1_N = 4096l * 1024, WFF2_N = 1024l * 4096;
    const size_t welems = WQKV_N + WOUT_N + WFF1_N + WFF2_N;

    // chunk rows R: multiple of lcm(7,256)=1792; per-chunk arena = R*14336 B + weights
    int nc = 1;
    while (nc < 16 && (size_t)(MTOT / nc) * 14336 + welems * 2 > ws_size) nc <<= 1;
    const long R = MTOT / nc;

    char* ws = (char*)d_ws;
    ushort_t* qkv  = (ushort_t*)ws;                          // [R,3072]
    ushort_t* obuf = (ushort_t*)(ws + (size_t)R * 3072 * 2); // [R,1024]
    ushort_t* ff   = qkv;                                    // [R,4096] reuses qkv+obuf
    ushort_t* ybuf = (ushort_t*)(ws + (size_t)R * 4096 * 2); // [R,1024]
    ushort_t* s2   = (ushort_t*)(ws + (size_t)R * 5120 * 2); // [R,1024]
    ushort_t* xb   = (ushort_t*)(ws + (size_t)R * 6144 * 2); // [R,1024]
    ushort_t* wq   = (ushort_t*)(ws + (size_t)R * 7168 * 2);
    ushort_t* wo   = wq + WQKV_N;
    ushort_t* w1   = wo + WOUT_N;
    ushort_t* w2   = w1 + WFF1_N;

    // merged weight conversion: (WQKV+WOUT+WFF1+WFF2)/4 float4s = 3145728 -> 12288 blocks
    f2b4_kernel<<<12288, 256, 0, stream>>>(wqkv_f, wq, wout_f, wo, wff1_f, w1, wff2_f, w2);

    for (int c = 0; c < nc; ++c) {
        const float* xc = x + (size_t)c * R * H_;
        float* oc = out + (size_t)c * R * H_;
        const int GY = R / 256;
        f2b_kernel<<<(R * H_) / 1024, 256, 0, stream>>>(xc, xb);
        // qkv = x @ Wqkv^T + b
        gemm_bt<0, float><<<12 * GY, 512, 0, stream>>>(xb, wq, bqkv, (const float*)nullptr, qkv, 3072, 1024, 12);
        // windowed attention
        attn_kernel<<<(R / 7) * 16, 64, 0, stream>>>(qkv, obuf);
        // s1 = x + o @ Wout^T + b   (residual from bf16 xb: -58MB fetch, err negligible)
        gemm_bt<2, ushort_t><<<4 * GY, 512, 0, stream>>>(obuf, wo, bout, xb, ybuf, 1024, 1024, 4);
        // y = LN1(s1), in place
        ln_kernel<ushort_t><<<R, 256, 0, stream>>>(ybuf, ybuf, ln1g, ln1b);
        // ff = relu(y @ W1^T + b1)
        gemm_bt<1, float><<<16 * GY, 512, 0, stream>>>(ybuf, w1, bff1, (const float*)nullptr, ff, 4096, 1024, 16);
        // s2 = y + ff @ W2^T + b2
        gemm_bt<2, ushort_t><<<4 * GY, 512, 0, stream>>>(ff, w2, bff2, ybuf, s2, 1024, 4096, 4);
        // out = LN2(s2), fp32
        ln_kernel<float><<<R, 256, 0, stream>>>(s2, oc, ln2g, ln2b);
    }
}